// Round 11
// baseline (2365.635 us; speedup 1.0000x reference)
//
#include <hip/hip_runtime.h>

// LSTM_87771951661891: persistent kernel, static XCD-local data exchange.
// Bet (m157/m192-backed): blockIdx % 8 == XCD. XCD x hosts blocks {x,x+8,...}:
// 32 blocks = 2 sync-groups of 16, all sharing one L2. h-data exchange uses
// sc0-only ops (L1 bypass, LOCAL L2 coherence point: fast store-ack + loads).
// Flags keep R8's agent-scope (sc1/MALL) atomics: replay-safe via host memset,
// no new unbounded waits. Wrong placement bet => stale data => visible absmax
// failure, never a hang. Everything else identical to the proven R8 kernel.

#define TN 512
#define BM 256
#define HD 512
#define ID 256

typedef __attribute__((ext_vector_type(8))) __bf16 bf16x8;
typedef __attribute__((ext_vector_type(4))) __bf16 bf16x4;
typedef __attribute__((ext_vector_type(4))) unsigned int u32x4;
typedef __attribute__((ext_vector_type(4))) float f32x4;

union ABits { u32x4 u; bf16x8 b; };
union U64x1 { bf16x4 v; unsigned long long q; };

__device__ __forceinline__ float sigm(float x) { return 1.f / (1.f + __expf(-x)); }
__device__ __forceinline__ float tanh_fast(float x) { return 1.f - 2.f / (__expf(2.f * x) + 1.f); }

// sc0-only 8B store: dirty line in the LOCAL XCD L2 (coherence point for the group)
__device__ __forceinline__ void store_h64(__bf16* p, unsigned long long v) {
    asm volatile("global_store_dwordx2 %0, %1, off sc0" :: "v"(p), "v"(v) : "memory");
}

__global__ void __launch_bounds__(256, 1)
lstm_persist(const float* __restrict__ x_in, const int* __restrict__ bs_in,
             const float* __restrict__ h0, const float* __restrict__ c0,
             const float* __restrict__ tau_p, const float* __restrict__ Ww,
             const float* __restrict__ Wb, const float* __restrict__ Uw,
             float* __restrict__ out, __bf16* __restrict__ hbuf,
             int* __restrict__ flags)
{
    __shared__ int   bs_lds[TN];
    __shared__ float x0_lds[16][ID + 1];            // prologue only
    __shared__ float hn_patch[4][16][9];            // per-wave h_new transpose patch
    __shared__ __align__(16) __bf16 htile[16][520]; // staged h tile (+16B row pad)

    const int tid  = threadIdx.x;
    const int lane = tid & 63;
    const int w    = tid >> 6;           // wave 0..3
    const int bid  = blockIdx.x;

    // static XCD-pure grouping: XCD x = bid&7 hosts in-XCD index ii = bid>>3 (0..31)
    const int xcd = bid & 7;
    const int ii  = bid >> 3;
    const int mg  = xcd * 2 + (ii >> 4); // sync-group (16 blocks, one XCD)
    const int jb  = ii & 15;             // j-block within group

    const int row0 = mg * 16;
    const int j0   = jb * 32;
    const int l15  = lane & 15;          // MFMA row (m) / B-frag col
    const int kg   = lane >> 4;          // k-chunk id; hidden-subcol in output
    const int gq   = lane & 3;           // ub build: gate index of MFMA-col l15
    const int jjq  = l15 >> 2;           // ub build: hidden-subcol of MFMA-col l15
    const float tau = tau_p[0];

    // staging assignment: wave w stages rows 4w..4w+3; lane -> (row, 16B slot)
    const int srow = 4 * w + (lane >> 4);
    const int scol = (lane & 15) * 8;

    // ---------------- prologue ----------------
    for (int i = tid; i < TN; i += 256) bs_lds[i] = bs_in[i];
    for (int s = tid; s < 16 * (ID / 4); s += 256) {
        int r = s >> 6, cs = s & 63;
        *reinterpret_cast<float4*>(&x0_lds[r][cs * 4]) =
            reinterpret_cast<const float4*>(x_in + (size_t)(row0 + r) * ID)[cs];
    }
    __syncthreads();

    // Gx = x0 @ Ww + Wb for this lane's 8 output gates
    float gxv[2][4];
    {
        float a[2][4] = {};
        const int cbase = j0 + 8 * w + kg;
        for (int k = 0; k < ID; ++k) {
            float xv = x0_lds[l15][k];
            const float* wr = Ww + (size_t)k * 2048;
            #pragma unroll
            for (int g = 0; g < 4; ++g) {
                a[0][g] += xv * wr[g * HD + cbase];
                a[1][g] += xv * wr[g * HD + cbase + 4];
            }
        }
        #pragma unroll
        for (int g = 0; g < 4; ++g) {
            gxv[0][g] = a[0][g] + Wb[g * HD + cbase];
            gxv[1][g] = a[1][g] + Wb[g * HD + cbase + 4];
        }
    }

    // U slice -> registers (A-operand = U^T)
    bf16x8 ub[2][16];
    #pragma unroll
    for (int f = 0; f < 2; ++f) {
        const int ucol = gq * HD + j0 + 8 * w + 4 * f + jjq;
        #pragma unroll
        for (int ki = 0; ki < 16; ++ki) {
            const int kb = ki * 32 + kg * 8;
            bf16x8 v;
            #pragma unroll
            for (int e = 0; e < 8; ++e) v[e] = (__bf16)Uw[(size_t)(kb + e) * 2048 + ucol];
            ub[f][ki] = v;
        }
    }

    // c state: lane-local, (row m=l15, col j0+8w+4f+kg)
    float creg[2];
    #pragma unroll
    for (int f = 0; f < 2; ++f)
        creg[f] = c0[(size_t)(row0 + l15) * HD + j0 + 8 * w + 4 * f + kg];

    // store-lane setup (lane<32): r=lane>>1, s=lane&1 -> 4 cols jc..jc+3
    const int sr = lane >> 1, ss = lane & 1;
    const int jc = j0 + 8 * w + 4 * ss;
    const bool is_store = (lane < 32);
    const bool owner = (jb == 0) && (w == 0) && (ss == 0) && is_store;
    float hprev[4] = {0.f, 0.f, 0.f, 0.f};
    float hxy0 = 0.f, hxy1 = 0.f;

    if (is_store) {
        float4 v = *reinterpret_cast<const float4*>(h0 + (size_t)(row0 + sr) * HD + jc);
        hprev[0] = v.x; hprev[1] = v.y; hprev[2] = v.z; hprev[3] = v.w;
        if (owner) { hxy0 = v.x; hxy1 = v.y; }
        U64x1 sv;
        #pragma unroll
        for (int c = 0; c < 4; ++c) sv.v[c] = (__bf16)hprev[c];
        store_h64(hbuf + (size_t)(row0 + sr) * HD + jc, sv.q);
    }
    asm volatile("s_waitcnt vmcnt(0)" ::: "memory");
    __builtin_amdgcn_sched_barrier(0);
    if (lane == 0)
        __hip_atomic_store(&flags[mg * 64 + jb * 4 + w], 1,
                           __ATOMIC_RELAXED, __HIP_MEMORY_SCOPE_AGENT);

    // ---------------- main sequential loop ----------------
    for (int t = 0; t < TN; ++t) {
        const __bf16* base_p = hbuf + (size_t)(t & 1) * (BM * HD);
        __bf16*       base_n = hbuf + (size_t)((t + 1) & 1) * (BM * HD);
        const int bs_t = bs_lds[t];

        // fp32 xcorr side-channel advance (owner lanes; harmless elsewhere)
        if (t != 0) {
            float xs0 = hxy0, xs1 = hxy1;
            hxy0 = xs0 + tau * (1.5f * xs0 + 0.66666667f * xs1);
            hxy1 = xs1 + tau * (-1.5f * xs0);
        }

        // spin (bounded insurance): all 64 producer-wave flags >= t+1 (MALL path)
        for (int it = 0; it < (1 << 20); ++it) {
            int v = __hip_atomic_load(&flags[mg * 64 + lane],
                                      __ATOMIC_RELAXED, __HIP_MEMORY_SCOPE_AGENT);
            if (__all(v >= t + 1)) break;
            __builtin_amdgcn_s_sleep(1);
        }

        // cooperative sc0 stage (local-L2 read): wave w loads rows 4w..4w+3 into LDS
        {
            const __bf16* srcp = base_p + (size_t)(row0 + srow) * HD + scol;
            u32x4 s0, s1, s2, s3;
            asm volatile(
                "global_load_dwordx4 %0, %[p], off sc0\n\t"
                "global_load_dwordx4 %1, %[p], off offset:256 sc0\n\t"
                "global_load_dwordx4 %2, %[p], off offset:512 sc0\n\t"
                "global_load_dwordx4 %3, %[p], off offset:768 sc0\n\t"
                "s_waitcnt vmcnt(0)"
                : "=&v"(s0), "=&v"(s1), "=&v"(s2), "=&v"(s3)
                : [p] "v"(srcp)
                : "memory");
            __builtin_amdgcn_sched_barrier(0);
            ABits tb;
            tb.u = s0; *reinterpret_cast<bf16x8*>(&htile[srow][scol])       = tb.b;
            tb.u = s1; *reinterpret_cast<bf16x8*>(&htile[srow][scol + 128]) = tb.b;
            tb.u = s2; *reinterpret_cast<bf16x8*>(&htile[srow][scol + 256]) = tb.b;
            tb.u = s3; *reinterpret_cast<bf16x8*>(&htile[srow][scol + 384]) = tb.b;
        }
        __syncthreads();

        // h fragments from LDS
        bf16x8 ah[16];
        #pragma unroll
        for (int ki = 0; ki < 16; ++ki)
            ah[ki] = *reinterpret_cast<const bf16x8*>(&htile[l15][ki * 32 + kg * 8]);

        // read-side xcorr on k=0,1 (all rows; t!=0), fp32
        if (t != 0 && kg == 0) {
            float xs0 = (float)ah[0][0];
            float xs1 = (float)ah[0][1];
            ah[0][0] = (__bf16)(xs0 + tau * (1.5f * xs0 + 0.66666667f * xs1));
            ah[0][1] = (__bf16)(xs1 + tau * (-1.5f * xs0));
        }

        // gates = U^T x h^T (swapped operands)
        f32x4 acc0 = {0.f, 0.f, 0.f, 0.f}, acc1 = {0.f, 0.f, 0.f, 0.f};
        #pragma unroll
        for (int ki = 0; ki < 16; ++ki) {
            acc0 = __builtin_amdgcn_mfma_f32_16x16x32_bf16(ub[0][ki], ah[ki], acc0, 0, 0, 0);
            acc1 = __builtin_amdgcn_mfma_f32_16x16x32_bf16(ub[1][ki], ah[ki], acc1, 0, 0, 0);
        }

        // pointwise: fully lane-local
        const bool act_m = (row0 + l15) < bs_t;
        #pragma unroll
        for (int f = 0; f < 2; ++f) {
            const f32x4 a = f ? acc1 : acc0;
            float gi = a[0] + gxv[f][0];
            float gf = a[1] + gxv[f][1];
            float gg = a[2] + gxv[f][2];
            float go = a[3] + gxv[f][3];
            float cn = sigm(gf) * creg[f] + sigm(gi) * tanh_fast(gg);
            float hn = sigm(go) * tanh_fast(cn);
            if (act_m) creg[f] = cn;
            hn_patch[w][l15][4 * f + kg] = hn;
        }

        // wave-local transpose barrier (same-wave LDS ordering only)
        asm volatile("s_waitcnt lgkmcnt(0)" ::: "memory");
        __builtin_amdgcn_sched_barrier(0);

        // store phase: lanes 0..31, row sr, cols jc..jc+3 (sc0 store, fast L2 ack)
        if (is_store) {
            const bool act_r = (row0 + sr) < bs_t;
            float hn0 = hn_patch[w][sr][4 * ss + 0];
            float hn1 = hn_patch[w][sr][4 * ss + 1];
            float hn2 = hn_patch[w][sr][4 * ss + 2];
            float hn3 = hn_patch[w][sr][4 * ss + 3];
            float hv[4];
            hv[0] = act_r ? hn0 : hprev[0];
            hv[1] = act_r ? hn1 : hprev[1];
            hv[2] = act_r ? hn2 : hprev[2];
            hv[3] = act_r ? hn3 : hprev[3];
            if (owner) {
                if (act_r) { hxy0 = hn0; hxy1 = hn1; }
                else       { hv[0] = hxy0; hv[1] = hxy1; }
            }
            #pragma unroll
            for (int c = 0; c < 4; ++c) hprev[c] = hv[c];
            U64x1 sv;
            #pragma unroll
            for (int c = 0; c < 4; ++c) sv.v[c] = (__bf16)hv[c];
            store_h64(base_n + (size_t)(row0 + sr) * HD + jc, sv.q);
            asm volatile("s_waitcnt vmcnt(0)" ::: "memory");
            __builtin_amdgcn_sched_barrier(0);
            if (lane == 0)
                __hip_atomic_store(&flags[mg * 64 + jb * 4 + w], t + 2,
                                   __ATOMIC_RELAXED, __HIP_MEMORY_SCOPE_AGENT);
            // outputs[t] (off the inter-block critical path)
            float4 q;
            q.x = act_r ? hn0 : 0.f; q.y = act_r ? hn1 : 0.f;
            q.z = act_r ? hn2 : 0.f; q.w = act_r ? hn3 : 0.f;
            *reinterpret_cast<float4*>(out + (size_t)t * (BM * HD)
                                       + (size_t)(row0 + sr) * HD + jc) = q;
        }
    }

    // ---------------- epilogue ----------------
    if (is_store) {
        float4 p;
        p.x = hprev[0]; p.y = hprev[1]; p.z = hprev[2]; p.w = hprev[3];
        *reinterpret_cast<float4*>(out + (size_t)TN * BM * HD
                                   + (size_t)(row0 + sr) * HD + jc) = p;
    }
    {
        float* cp = out + (size_t)TN * BM * HD + (size_t)BM * HD;
        #pragma unroll
        for (int f = 0; f < 2; ++f)
            cp[(size_t)(row0 + l15) * HD + j0 + 8 * w + 4 * f + kg] = creg[f];
    }
}

extern "C" void kernel_launch(void* const* d_in, const int* in_sizes, int n_in,
                              void* d_out, int out_size, void* d_ws, size_t ws_size,
                              hipStream_t stream) {
    const float* x_in = (const float*)d_in[0];
    const int*   bs   = (const int*)d_in[1];
    const float* h0   = (const float*)d_in[2];
    const float* c0   = (const float*)d_in[3];
    const float* tau  = (const float*)d_in[4];
    const float* Ww   = (const float*)d_in[5];
    const float* Wb   = (const float*)d_in[6];
    const float* Uw   = (const float*)d_in[7];
    float* out = (float*)d_out;

    int*    flags = (int*)d_ws;                      // 16 groups x 64 flags = 4 KB (MALL-reset)
    __bf16* hbuf  = (__bf16*)((char*)d_ws + 4096);   // 2 bufs x 256 x 512 bf16 = 512 KB

    (void)hipMemsetAsync(d_ws, 0, 4096, stream);

    hipLaunchKernelGGL(lstm_persist, dim3(256), dim3(256), 0, stream,
                       x_in, bs, h0, c0, tau, Ww, Wb, Uw, out, hbuf, flags);
}